// Round 11
// baseline (32.394 us; speedup 1.0000x reference)
//
#include <hip/hip_runtime.h>
#include <hip/hip_bf16.h>
#include <math.h>

#define D 256
#define S 4096
#define BATCH 4
#define RPB 32                    // rows per band block
#define NBLK (BATCH * S / RPB)    // 512 band blocks
#define DT_CUT 7.0f

typedef __attribute__((ext_vector_type(8))) short short8;
typedef __attribute__((ext_vector_type(4))) float f32x4;

static __device__ __forceinline__ unsigned short f2bf(float x) {
    union { __hip_bfloat16 b; unsigned short u; } cv;
    cv.b = __float2bfloat16(x);    // HW RNE convert
    return cv.u;
}

// ===========================================================================
// Fragment-tiled layouts (every MFMA fragment = one contiguous coalesced
// 1KB wave transaction):
//   emb5: tile ((b*128 + jc)*16 + (w*4 + nt)), elem = lane*8 + e
//         (b, j = jc*32 + (lane>>4)*8 + e, d = w*64 + nt*16 + (lane&15))
//   w5:   tile (et16*8 + kt), elem = lane*8 + ee
//         (e = et16*16 + (lane&15), d = kt*32 + (lane>>4)*8 + ee)
//   H5:   tile (rb*8 + kt),  elem = lane*8 + ee      [decoder A-operand]
//         (row = rb*16 + (lane&15), d = kt*32 + (lane>>4)*8 + ee)
// ===========================================================================

// ---------------------------------------------------------------------------
// K1: embedding -> emb5 (LDS-staged scatter, coalesced stream-out);
// W -> w5 (blk < 256); band-start jcmin per band block (wave 0).
// ---------------------------------------------------------------------------
__global__ __launch_bounds__(256) void embt_kernel(const float* __restrict__ t,
                                                   const float* __restrict__ W,
                                                   unsigned short* __restrict__ emb5,
                                                   unsigned short* __restrict__ w5,
                                                   int* __restrict__ jcmin_out) {
    int blk = blockIdx.x;
    int tid = threadIdx.x;

    if (blk < 256) {               // W[e][d] -> w5 fragment tiles
        int e = blk, dd = tid;
        int et16 = e >> 4, l15 = e & 15;
        int kt = dd >> 5, kgg = (dd >> 3) & 3, ee = dd & 7;
        w5[(size_t)((et16 * 8 + kt) * 512) + (kgg * 16 + l15) * 8 + ee]
            = f2bf(W[e * D + dd]);
    }

    // wave 0: band-start search for band block == blk
    if (tid < 64) {
        int b2 = blk >> 7;
        int i0 = (blk & 127) * RPB;
        const float* tb2 = t + b2 * S;
        float tcut = tb2[i0] - DT_CUT;
        int lo = 0, hi = i0;                 // invariant: t[hi] >= tcut
        while (hi > lo) {
            int step = ((hi - lo) + 63) >> 6;
            int p = min(lo + tid * step, hi);
            unsigned long long mb = __ballot(tb2[p] < tcut);
            int cnt = __popcll(mb);
            int nlo = (cnt == 0) ? lo : (lo + (cnt - 1) * step + 1);
            int nhi = (cnt == 0) ? nlo : min(lo + cnt * step, hi);
            lo = nlo; hi = nhi;
        }
        if (tid == 0) jcmin_out[blk] = lo >> 5;
    }

    __shared__ unsigned short tile[8192];       // 16 KiB, final global order
    int j_local = tid & 31;
    int fg      = tid >> 5;                     // 8 groups x 16 freqs
    int b       = blk >> 7;
    int jc      = blk & 127;
    float tv = t[b * S + jc * 32 + j_local];
    int kg = j_local >> 3, e = j_local & 7;
    const float c2 = -0.1038102552f;            // -2*log2(10000)/256
#pragma unroll
    for (int kk = 0; kk < 16; ++kk) {
        int k = fg * 16 + kk;
        float te = tv * exp2f(c2 * (float)(k + 1));
        float sn, cs;
        __sincosf(te, &sn, &cs);
        int base = (k >> 3) * 512 + kg * 128 + e;
        int ln0 = 2 * (k & 7);
        tile[base + ln0 * 8]       = f2bf(sn);         // d even -> sin
        tile[base + (ln0 + 1) * 8] = f2bf(cs);         // d odd  -> cos
    }
    __syncthreads();
    const uint4* src = (const uint4*)tile;             // 1024 x 16B
    uint4* dst = (uint4*)(emb5 + (size_t)blk * 8192);
#pragma unroll
    for (int p = 0; p < 4; ++p) dst[p * 256 + tid] = src[p * 256 + tid];
}

// ---------------------------------------------------------------------------
// K2: band GEMM + LayerNorm -> H5 (decoder-fragment layout).
// Block = 32 rows (2 Mt tiles) x 256 d, 4 waves = d-slices. 2-deep pipelined
// fully-causal loop; diagonal chunk peeled. XCD-swizzled block ids.
// ---------------------------------------------------------------------------
__global__ __launch_bounds__(256, 4) void band_kernel(
    const float* __restrict__ t, const unsigned short* __restrict__ emb5,
    const int* __restrict__ jcmin_arr,
    const float* __restrict__ gamma, const float* __restrict__ beta,
    unsigned short* __restrict__ H5) {
    int bid  = blockIdx.x;
    int blk  = (bid & 7) * (NBLK / 8) + (bid >> 3);   // XCD swizzle (bijective)
    int b    = blk >> 7;                 // 128 blocks per batch
    int i0   = (blk & 127) * RPB;
    int tid  = threadIdx.x;
    int w    = tid >> 6;
    int lane = tid & 63;
    int ln15 = lane & 15;
    int kg   = lane >> 4;
    const float* tb = t + b * S;

    float ti0 = tb[i0 + ln15], ti1 = tb[i0 + 16 + ln15];
    int   ir0 = i0 + ln15,     ir1 = i0 + 16 + ln15;
    int jcmin = jcmin_arr[blk];
    int jcmax = i0 >> 5;                 // last (diagonal) chunk

    f32x4 acc[2][4];
#pragma unroll
    for (int Mt = 0; Mt < 2; ++Mt)
#pragma unroll
        for (int nt = 0; nt < 4; ++nt) acc[Mt][nt] = (f32x4){0.f, 0.f, 0.f, 0.f};

    const unsigned short* ebase =
        emb5 + ((size_t)(b * 128) * 16 + w * 4) * 512 + lane * 8;
    short8 c0, c1, c2, c3;
    float4 ta4, tb4;
    {
        const unsigned short* p = ebase + (size_t)jcmin * 8192;
        c0 = *(const short8*)(p);
        c1 = *(const short8*)(p + 512);
        c2 = *(const short8*)(p + 1024);
        c3 = *(const short8*)(p + 1536);
        ta4 = *(const float4*)&tb[jcmin * 32 + kg * 8];
        tb4 = *(const float4*)&tb[jcmin * 32 + kg * 8 + 4];
    }
    // fully-causal chunks (j0 + 31 < i0 for both Mt tiles)
    for (int jc = jcmin; jc < jcmax; ++jc) {
        const unsigned short* p = ebase + (size_t)(jc + 1) * 8192;
        short8 n0 = *(const short8*)(p);
        short8 n1 = *(const short8*)(p + 512);
        short8 n2 = *(const short8*)(p + 1024);
        short8 n3 = *(const short8*)(p + 1536);
        float4 nta = *(const float4*)&tb[jc * 32 + 32 + kg * 8];
        float4 ntb = *(const float4*)&tb[jc * 32 + 32 + kg * 8 + 4];

        float tj[8] = {ta4.x, ta4.y, ta4.z, ta4.w, tb4.x, tb4.y, tb4.z, tb4.w};
        union { short8 v; unsigned short u[8]; } a0, a1;
#pragma unroll
        for (int e = 0; e < 8; ++e) {
            float d0 = ti0 - tj[e], d1 = ti1 - tj[e];
            a0.u[e] = f2bf(__expf(-0.5f * d0 * d0));
            a1.u[e] = f2bf(__expf(-0.5f * d1 * d1));
        }
        acc[0][0] = __builtin_amdgcn_mfma_f32_16x16x32_bf16(a0.v, c0, acc[0][0], 0, 0, 0);
        acc[0][1] = __builtin_amdgcn_mfma_f32_16x16x32_bf16(a0.v, c1, acc[0][1], 0, 0, 0);
        acc[0][2] = __builtin_amdgcn_mfma_f32_16x16x32_bf16(a0.v, c2, acc[0][2], 0, 0, 0);
        acc[0][3] = __builtin_amdgcn_mfma_f32_16x16x32_bf16(a0.v, c3, acc[0][3], 0, 0, 0);
        acc[1][0] = __builtin_amdgcn_mfma_f32_16x16x32_bf16(a1.v, c0, acc[1][0], 0, 0, 0);
        acc[1][1] = __builtin_amdgcn_mfma_f32_16x16x32_bf16(a1.v, c1, acc[1][1], 0, 0, 0);
        acc[1][2] = __builtin_amdgcn_mfma_f32_16x16x32_bf16(a1.v, c2, acc[1][2], 0, 0, 0);
        acc[1][3] = __builtin_amdgcn_mfma_f32_16x16x32_bf16(a1.v, c3, acc[1][3], 0, 0, 0);
        c0 = n0; c1 = n1; c2 = n2; c3 = n3;
        ta4 = nta; tb4 = ntb;
    }
    {   // diagonal chunk jc == jcmax (data already resident)
        int j0 = jcmax * 32;
        float tj[8] = {ta4.x, ta4.y, ta4.z, ta4.w, tb4.x, tb4.y, tb4.z, tb4.w};
        union { short8 v; unsigned short u[8]; } a0, a1;
#pragma unroll
        for (int e = 0; e < 8; ++e) {
            int j = j0 + kg * 8 + e;
            float d0 = ti0 - tj[e], d1 = ti1 - tj[e];
            float s0 = __expf(-0.5f * d0 * d0), s1 = __expf(-0.5f * d1 * d1);
            a0.u[e] = (j <= ir0) ? f2bf(s0) : (unsigned short)0;
            a1.u[e] = (j <= ir1) ? f2bf(s1) : (unsigned short)0;
        }
        acc[0][0] = __builtin_amdgcn_mfma_f32_16x16x32_bf16(a0.v, c0, acc[0][0], 0, 0, 0);
        acc[0][1] = __builtin_amdgcn_mfma_f32_16x16x32_bf16(a0.v, c1, acc[0][1], 0, 0, 0);
        acc[0][2] = __builtin_amdgcn_mfma_f32_16x16x32_bf16(a0.v, c2, acc[0][2], 0, 0, 0);
        acc[0][3] = __builtin_amdgcn_mfma_f32_16x16x32_bf16(a0.v, c3, acc[0][3], 0, 0, 0);
        acc[1][0] = __builtin_amdgcn_mfma_f32_16x16x32_bf16(a1.v, c0, acc[1][0], 0, 0, 0);
        acc[1][1] = __builtin_amdgcn_mfma_f32_16x16x32_bf16(a1.v, c1, acc[1][1], 0, 0, 0);
        acc[1][2] = __builtin_amdgcn_mfma_f32_16x16x32_bf16(a1.v, c2, acc[1][2], 0, 0, 0);
        acc[1][3] = __builtin_amdgcn_mfma_f32_16x16x32_bf16(a1.v, c3, acc[1][3], 0, 0, 0);
    }

    // ---- LayerNorm (row r = Mt*16 + kg*4 + reg; col d = w*64 + nt*16 + ln15)
    __shared__ float2 s_ln[4][RPB];
    __shared__ unsigned short H[RPB][264];       // +8 pad
#pragma unroll
    for (int Mt = 0; Mt < 2; ++Mt)
#pragma unroll
        for (int reg = 0; reg < 4; ++reg) {
            float s = acc[Mt][0][reg] + acc[Mt][1][reg] + acc[Mt][2][reg] + acc[Mt][3][reg];
            float q = acc[Mt][0][reg] * acc[Mt][0][reg] + acc[Mt][1][reg] * acc[Mt][1][reg]
                    + acc[Mt][2][reg] * acc[Mt][2][reg] + acc[Mt][3][reg] * acc[Mt][3][reg];
#pragma unroll
            for (int m = 1; m < 16; m <<= 1) {
                s += __shfl_xor(s, m);
                q += __shfl_xor(q, m);
            }
            if (ln15 == 0) s_ln[w][Mt * 16 + kg * 4 + reg] = make_float2(s, q);
        }
    __syncthreads();

    float g[4], be[4];
#pragma unroll
    for (int nt = 0; nt < 4; ++nt) {
        g[nt]  = gamma[w * 64 + nt * 16 + ln15];
        be[nt] = beta[w * 64 + nt * 16 + ln15];
    }
#pragma unroll
    for (int Mt = 0; Mt < 2; ++Mt)
#pragma unroll
        for (int reg = 0; reg < 4; ++reg) {
            int r = Mt * 16 + kg * 4 + reg;
            float2 p0 = s_ln[0][r], p1 = s_ln[1][r], p2 = s_ln[2][r], p3 = s_ln[3][r];
            float sum = p0.x + p1.x + p2.x + p3.x;
            float sq  = p0.y + p1.y + p2.y + p3.y;
            float mu  = sum * (1.0f / D);
            float var = fmaxf(sq * (1.0f / D) - mu * mu, 0.0f);
            float rstd = rsqrtf(var + 1e-6f);
#pragma unroll
            for (int nt = 0; nt < 4; ++nt) {
                float h = (acc[Mt][nt][reg] - mu) * rstd * g[nt] + be[nt];
                H[r][w * 64 + nt * 16 + ln15] = f2bf(h);
            }
        }
    __syncthreads();

    // ---- stream H out in decoder A-fragment layout (H5)
#pragma unroll
    for (int p = 0; p < 4; ++p) {
        int f = p * 256 + tid;
        int tl = f >> 6;                    // 16 tiles (rb*8 + kt)
        int l2 = f & 63;
        int rb = tl >> 3, kt = tl & 7;
        int kg2 = l2 >> 4, l15 = l2 & 15;
        uint4 v = *(const uint4*)&H[rb * 16 + l15][kt * 32 + kg2 * 8];
        *(uint4*)(H5 + (size_t)blk * 8192 + (size_t)f * 8) = v;
    }
}

// ---------------------------------------------------------------------------
// K3: decoder GEMM + softplus. 256 blocks x 64 rows, 512 threads (8 waves).
// Wave w owns e-slice [w*32, w*32+32): 2 et tiles; its 16 W-frags held in
// registers (loaded once); H staged once in 32KB LDS shared by all waves.
// ---------------------------------------------------------------------------
__global__ __launch_bounds__(512) void decoder_kernel(
    const unsigned short* __restrict__ H5, const unsigned short* __restrict__ w5,
    const float* __restrict__ w_t, const float* __restrict__ b_t,
    float* __restrict__ out) {
    int blkD = blockIdx.x;
    int tid  = threadIdx.x;
    int w    = tid >> 6;          // 0..7
    int lane = tid & 63;
    int ln15 = lane & 15;
    int kg   = lane >> 4;

    __shared__ unsigned short Ald[16384];   // 32 KiB: this block's 64 H rows
    __shared__ float s_part[8][64];

    // stage H5 block slice (coalesced), W frags concurrently
    const uint4* src = (const uint4*)(H5 + (size_t)blkD * 16384);
#pragma unroll
    for (int p = 0; p < 4; ++p) ((uint4*)Ald)[p * 512 + tid] = src[p * 512 + tid];

    short8 wfr[2][8];
#pragma unroll
    for (int etL = 0; etL < 2; ++etL)
#pragma unroll
        for (int kt = 0; kt < 8; ++kt)
            wfr[etL][kt] = *(const short8*)(
                w5 + (size_t)(((2 * w + etL) * 8 + kt) * 512) + lane * 8);

    float wt2[2];
    wt2[0] = w_t[w * 32 + ln15];
    wt2[1] = w_t[w * 32 + 16 + ln15];
    __syncthreads();

#pragma unroll
    for (int rg = 0; rg < 4; ++rg) {
        short8 af[8];
#pragma unroll
        for (int kt = 0; kt < 8; ++kt)
            af[kt] = *(const short8*)&Ald[(rg * 8 + kt) * 512 + lane * 8];
        f32x4 a0 = (f32x4){0.f, 0.f, 0.f, 0.f};
        f32x4 a1 = (f32x4){0.f, 0.f, 0.f, 0.f};
#pragma unroll
        for (int kt = 0; kt < 8; ++kt) {
            a0 = __builtin_amdgcn_mfma_f32_16x16x32_bf16(af[kt], wfr[0][kt], a0, 0, 0, 0);
            a1 = __builtin_amdgcn_mfma_f32_16x16x32_bf16(af[kt], wfr[1][kt], a1, 0, 0, 0);
        }
#pragma unroll
        for (int reg = 0; reg < 4; ++reg) {
            float v = fmaf(fmaxf(a0[reg], 0.f), wt2[0], fmaxf(a1[reg], 0.f) * wt2[1]);
#pragma unroll
            for (int m = 1; m < 16; m <<= 1) v += __shfl_xor(v, m);
            if (ln15 == 0) s_part[w][rg * 16 + kg * 4 + reg] = v;
        }
    }
    __syncthreads();
    if (tid < 64) {
        float tot = b_t[0];
#pragma unroll
        for (int ww = 0; ww < 8; ++ww) tot += s_part[ww][tid];
        float o = fmaxf(tot, 0.0f) + log1pf(expf(-fabsf(tot)));   // softplus
        out[(size_t)blkD * 64 + tid] = o;
    }
}

// ---------------------------------------------------------------------------
extern "C" void kernel_launch(void* const* d_in, const int* in_sizes, int n_in,
                              void* d_out, int out_size, void* d_ws, size_t ws_size,
                              hipStream_t stream) {
    // inputs: 0 event_type(i32) 1 event_time(f32) 2 arrival_times(f32)
    //         3 W_in 4 w_t 5 b_t 6 ln_gamma 7 ln_beta
    const float* t   = (const float*)d_in[1];
    const float* W   = (const float*)d_in[3];
    const float* wt  = (const float*)d_in[4];
    const float* bt  = (const float*)d_in[5];
    const float* gam = (const float*)d_in[6];
    const float* bet = (const float*)d_in[7];
    float* out = (float*)d_out;

    char* ws = (char*)d_ws;
    unsigned short* emb5  = (unsigned short*)ws;                        // 8 MiB
    unsigned short* w5    = (unsigned short*)(ws + (size_t)8388608);    // 128 KiB
    int*            jcmin = (int*)(ws + (size_t)8519680);               // 2 KiB
    unsigned short* H5    = (unsigned short*)(ws + (size_t)8527872);    // 8 MiB

    embt_kernel<<<dim3(512), dim3(256), 0, stream>>>(t, W, emb5, w5, jcmin);
    band_kernel<<<dim3(NBLK), dim3(256), 0, stream>>>(t, emb5, jcmin, gam, bet, H5);
    decoder_kernel<<<dim3(256), dim3(512), 0, stream>>>(H5, w5, wt, bt, out);
}

// Round 12
// 25.303 us; speedup vs baseline: 1.2802x; 1.2802x over previous
//
#include <hip/hip_runtime.h>
#include <hip/hip_bf16.h>
#include <math.h>

#define D 256
#define S 4096
#define BATCH 4
#define RPB 32                    // rows per fused block (2 Mt tiles)
#define NBLK (BATCH * S / RPB)    // 512 fused blocks
#define DT_CUT 7.0f

typedef __attribute__((ext_vector_type(8))) short short8;
typedef __attribute__((ext_vector_type(4))) float f32x4;

static __device__ __forceinline__ unsigned short f2bf(float x) {
    union { __hip_bfloat16 b; unsigned short u; } cv;
    cv.b = __float2bfloat16(x);    // HW RNE convert
    return cv.u;
}

// ===========================================================================
// Fragment-tiled layouts (every MFMA fragment = one contiguous coalesced
// 1KB wave transaction):
//   emb5: tile ((b*128 + jc)*16 + (w*4 + nt)), elem = lane*8 + e
//         (b, j = jc*32 + (lane>>4)*8 + e, d = w*64 + nt*16 + (lane&15))
//   w5:   tile (et16*8 + kt), elem = lane*8 + ee
//         (e = et16*16 + (lane&15), d = kt*32 + (lane>>4)*8 + ee)
// ===========================================================================

// ---------------------------------------------------------------------------
// K1: embedding -> emb5 (LDS-staged scatter, coalesced stream-out);
// W -> w5 (blk < 256); band-start jcmin per fused block (wave 0).
// ---------------------------------------------------------------------------
__global__ __launch_bounds__(256) void embt_kernel(const float* __restrict__ t,
                                                   const float* __restrict__ W,
                                                   unsigned short* __restrict__ emb5,
                                                   unsigned short* __restrict__ w5,
                                                   int* __restrict__ jcmin_out) {
    int blk = blockIdx.x;
    int tid = threadIdx.x;

    if (blk < 256) {               // W[e][d] -> w5 fragment tiles
        int e = blk, dd = tid;
        int et16 = e >> 4, l15 = e & 15;
        int kt = dd >> 5, kgg = (dd >> 3) & 3, ee = dd & 7;
        w5[(size_t)((et16 * 8 + kt) * 512) + (kgg * 16 + l15) * 8 + ee]
            = f2bf(W[e * D + dd]);
    }

    // wave 0: band-start search for fused block == blk
    if (tid < 64) {
        int b2 = blk >> 7;
        int i0 = (blk & 127) * RPB;
        const float* tb2 = t + b2 * S;
        float tcut = tb2[i0] - DT_CUT;
        int lo = 0, hi = i0;                 // invariant: t[hi] >= tcut
        while (hi > lo) {
            int step = ((hi - lo) + 63) >> 6;
            int p = min(lo + tid * step, hi);
            unsigned long long mb = __ballot(tb2[p] < tcut);
            int cnt = __popcll(mb);
            int nlo = (cnt == 0) ? lo : (lo + (cnt - 1) * step + 1);
            int nhi = (cnt == 0) ? nlo : min(lo + cnt * step, hi);
            lo = nlo; hi = nhi;
        }
        if (tid == 0) jcmin_out[blk] = lo >> 5;
    }

    __shared__ unsigned short tile[8192];       // 16 KiB, final global order
    int j_local = tid & 31;
    int fg      = tid >> 5;                     // 8 groups x 16 freqs
    int b       = blk >> 7;
    int jc      = blk & 127;
    float tv = t[b * S + jc * 32 + j_local];
    int kg = j_local >> 3, e = j_local & 7;
    const float c2 = -0.1038102552f;            // -2*log2(10000)/256
#pragma unroll
    for (int kk = 0; kk < 16; ++kk) {
        int k = fg * 16 + kk;
        float te = tv * exp2f(c2 * (float)(k + 1));
        float sn, cs;
        __sincosf(te, &sn, &cs);
        int base = (k >> 3) * 512 + kg * 128 + e;
        int ln0 = 2 * (k & 7);
        tile[base + ln0 * 8]       = f2bf(sn);         // d even -> sin
        tile[base + (ln0 + 1) * 8] = f2bf(cs);         // d odd  -> cos
    }
    __syncthreads();
    const uint4* src = (const uint4*)tile;             // 1024 x 16B
    uint4* dst = (uint4*)(emb5 + (size_t)blk * 8192);
#pragma unroll
    for (int p = 0; p < 4; ++p) dst[p * 256 + tid] = src[p * 256 + tid];
}

// ---------------------------------------------------------------------------
// K2: fused band-GEMM + LayerNorm + decoder-GEMM + softplus.
// Block = 32 rows (2 Mt) x 256 d/e, 4 waves. Band: 2-deep pipelined causal
// loop + peeled diagonal chunk. Decoder: register-pipelined W-frags reused
// across both Mt tiles. XCD-swizzled block ids.
// ---------------------------------------------------------------------------
__global__ __launch_bounds__(256) void fused_kernel(
    const float* __restrict__ t, const unsigned short* __restrict__ emb5,
    const unsigned short* __restrict__ w5, const int* __restrict__ jcmin_arr,
    const float* __restrict__ gamma, const float* __restrict__ beta,
    const float* __restrict__ w_t, const float* __restrict__ b_t,
    float* __restrict__ out) {
    int bid  = blockIdx.x;
    int blk  = (bid & 7) * (NBLK / 8) + (bid >> 3);   // XCD swizzle (bijective)
    int b    = blk >> 7;                 // 128 blocks per batch
    int i0   = (blk & 127) * RPB;
    int tid  = threadIdx.x;
    int w    = tid >> 6;
    int lane = tid & 63;
    int ln15 = lane & 15;
    int kg   = lane >> 4;
    const float* tb = t + b * S;

    float ti0 = tb[i0 + ln15], ti1 = tb[i0 + 16 + ln15];
    int   ir0 = i0 + ln15,     ir1 = i0 + 16 + ln15;
    int jcmin = jcmin_arr[blk];
    int jcmax = i0 >> 5;                 // last (diagonal) chunk

    // ---- band GEMM: C[m, d] += scores[m, k] * emb[k, d]
    f32x4 acc[2][4];
#pragma unroll
    for (int Mt = 0; Mt < 2; ++Mt)
#pragma unroll
        for (int nt = 0; nt < 4; ++nt) acc[Mt][nt] = (f32x4){0.f, 0.f, 0.f, 0.f};

    const unsigned short* ebase =
        emb5 + ((size_t)(b * 128) * 16 + w * 4) * 512 + lane * 8;
    short8 c0, c1, c2, c3;
    float4 ta4, tb4;
    {
        const unsigned short* p = ebase + (size_t)jcmin * 8192;
        c0 = *(const short8*)(p);
        c1 = *(const short8*)(p + 512);
        c2 = *(const short8*)(p + 1024);
        c3 = *(const short8*)(p + 1536);
        ta4 = *(const float4*)&tb[jcmin * 32 + kg * 8];
        tb4 = *(const float4*)&tb[jcmin * 32 + kg * 8 + 4];
    }
    // fully-causal chunks (j0 + 31 < i0), branch-free pipelined steady state
    for (int jc = jcmin; jc < jcmax; ++jc) {
        const unsigned short* p = ebase + (size_t)(jc + 1) * 8192;
        short8 n0 = *(const short8*)(p);
        short8 n1 = *(const short8*)(p + 512);
        short8 n2 = *(const short8*)(p + 1024);
        short8 n3 = *(const short8*)(p + 1536);
        float4 nta = *(const float4*)&tb[jc * 32 + 32 + kg * 8];
        float4 ntb = *(const float4*)&tb[jc * 32 + 32 + kg * 8 + 4];

        float tj[8] = {ta4.x, ta4.y, ta4.z, ta4.w, tb4.x, tb4.y, tb4.z, tb4.w};
        union { short8 v; unsigned short u[8]; } a0, a1;
#pragma unroll
        for (int e = 0; e < 8; ++e) {
            float d0 = ti0 - tj[e], d1 = ti1 - tj[e];
            a0.u[e] = f2bf(__expf(-0.5f * d0 * d0));
            a1.u[e] = f2bf(__expf(-0.5f * d1 * d1));
        }
        acc[0][0] = __builtin_amdgcn_mfma_f32_16x16x32_bf16(a0.v, c0, acc[0][0], 0, 0, 0);
        acc[0][1] = __builtin_amdgcn_mfma_f32_16x16x32_bf16(a0.v, c1, acc[0][1], 0, 0, 0);
        acc[0][2] = __builtin_amdgcn_mfma_f32_16x16x32_bf16(a0.v, c2, acc[0][2], 0, 0, 0);
        acc[0][3] = __builtin_amdgcn_mfma_f32_16x16x32_bf16(a0.v, c3, acc[0][3], 0, 0, 0);
        acc[1][0] = __builtin_amdgcn_mfma_f32_16x16x32_bf16(a1.v, c0, acc[1][0], 0, 0, 0);
        acc[1][1] = __builtin_amdgcn_mfma_f32_16x16x32_bf16(a1.v, c1, acc[1][1], 0, 0, 0);
        acc[1][2] = __builtin_amdgcn_mfma_f32_16x16x32_bf16(a1.v, c2, acc[1][2], 0, 0, 0);
        acc[1][3] = __builtin_amdgcn_mfma_f32_16x16x32_bf16(a1.v, c3, acc[1][3], 0, 0, 0);
        c0 = n0; c1 = n1; c2 = n2; c3 = n3;
        ta4 = nta; tb4 = ntb;
    }
    {   // peeled diagonal chunk jc == jcmax (operands already resident)
        int j0 = jcmax * 32;
        float tj[8] = {ta4.x, ta4.y, ta4.z, ta4.w, tb4.x, tb4.y, tb4.z, tb4.w};
        union { short8 v; unsigned short u[8]; } a0, a1;
#pragma unroll
        for (int e = 0; e < 8; ++e) {
            int j = j0 + kg * 8 + e;
            float d0 = ti0 - tj[e], d1 = ti1 - tj[e];
            float s0 = __expf(-0.5f * d0 * d0), s1 = __expf(-0.5f * d1 * d1);
            a0.u[e] = (j <= ir0) ? f2bf(s0) : (unsigned short)0;
            a1.u[e] = (j <= ir1) ? f2bf(s1) : (unsigned short)0;
        }
        acc[0][0] = __builtin_amdgcn_mfma_f32_16x16x32_bf16(a0.v, c0, acc[0][0], 0, 0, 0);
        acc[0][1] = __builtin_amdgcn_mfma_f32_16x16x32_bf16(a0.v, c1, acc[0][1], 0, 0, 0);
        acc[0][2] = __builtin_amdgcn_mfma_f32_16x16x32_bf16(a0.v, c2, acc[0][2], 0, 0, 0);
        acc[0][3] = __builtin_amdgcn_mfma_f32_16x16x32_bf16(a0.v, c3, acc[0][3], 0, 0, 0);
        acc[1][0] = __builtin_amdgcn_mfma_f32_16x16x32_bf16(a1.v, c0, acc[1][0], 0, 0, 0);
        acc[1][1] = __builtin_amdgcn_mfma_f32_16x16x32_bf16(a1.v, c1, acc[1][1], 0, 0, 0);
        acc[1][2] = __builtin_amdgcn_mfma_f32_16x16x32_bf16(a1.v, c2, acc[1][2], 0, 0, 0);
        acc[1][3] = __builtin_amdgcn_mfma_f32_16x16x32_bf16(a1.v, c3, acc[1][3], 0, 0, 0);
    }

    // ---- hoist decoder kt=0 weight frags (independent of LN barriers)
    const unsigned short* wbase = w5 + (size_t)(w * 4 * 8) * 512 + lane * 8;
    short8 w0 = *(const short8*)(wbase + (size_t)(0 * 8) * 512);
    short8 w1 = *(const short8*)(wbase + (size_t)(1 * 8) * 512);
    short8 w2 = *(const short8*)(wbase + (size_t)(2 * 8) * 512);
    short8 w3 = *(const short8*)(wbase + (size_t)(3 * 8) * 512);

    // ---- LayerNorm (row r = Mt*16 + kg*4 + reg; col d = w*64 + nt*16 + ln15)
    __shared__ float2 s_ln[4][RPB];
    __shared__ unsigned short H[RPB][264];       // +8 pad: conflict-free b128
    __shared__ float s_dec[4][RPB];

#pragma unroll
    for (int Mt = 0; Mt < 2; ++Mt)
#pragma unroll
        for (int reg = 0; reg < 4; ++reg) {
            float s = acc[Mt][0][reg] + acc[Mt][1][reg] + acc[Mt][2][reg] + acc[Mt][3][reg];
            float q = acc[Mt][0][reg] * acc[Mt][0][reg] + acc[Mt][1][reg] * acc[Mt][1][reg]
                    + acc[Mt][2][reg] * acc[Mt][2][reg] + acc[Mt][3][reg] * acc[Mt][3][reg];
#pragma unroll
            for (int m = 1; m < 16; m <<= 1) {
                s += __shfl_xor(s, m);
                q += __shfl_xor(q, m);
            }
            if (ln15 == 0) s_ln[w][Mt * 16 + kg * 4 + reg] = make_float2(s, q);
        }
    __syncthreads();

    float g[4], be[4];
#pragma unroll
    for (int nt = 0; nt < 4; ++nt) {
        g[nt]  = gamma[w * 64 + nt * 16 + ln15];
        be[nt] = beta[w * 64 + nt * 16 + ln15];
    }
#pragma unroll
    for (int Mt = 0; Mt < 2; ++Mt)
#pragma unroll
        for (int reg = 0; reg < 4; ++reg) {
            int r = Mt * 16 + kg * 4 + reg;
            float2 p0 = s_ln[0][r], p1 = s_ln[1][r], p2 = s_ln[2][r], p3 = s_ln[3][r];
            float sum = p0.x + p1.x + p2.x + p3.x;
            float sq  = p0.y + p1.y + p2.y + p3.y;
            float mu  = sum * (1.0f / D);
            float var = fmaxf(sq * (1.0f / D) - mu * mu, 0.0f);
            float rstd = rsqrtf(var + 1e-6f);
#pragma unroll
            for (int nt = 0; nt < 4; ++nt) {
                float h = (acc[Mt][nt][reg] - mu) * rstd * g[nt] + be[nt];
                H[r][w * 64 + nt * 16 + ln15] = f2bf(h);
            }
        }
    __syncthreads();

    // ---- decoder GEMM: C2[m, e] = sum_d H[m, d] * W[e, d], kt pipelined;
    //      W-frags reused across both Mt tiles.
    f32x4 acc2[2][4];
#pragma unroll
    for (int Mt = 0; Mt < 2; ++Mt)
#pragma unroll
        for (int et = 0; et < 4; ++et) acc2[Mt][et] = (f32x4){0.f, 0.f, 0.f, 0.f};

#pragma unroll
    for (int kt = 0; kt < 8; ++kt) {
        short8 nw0, nw1, nw2, nw3;
        if (kt < 7) {
            const unsigned short* p = wbase + (size_t)(kt + 1) * 512;
            nw0 = *(const short8*)(p + (size_t)(0 * 8) * 512);
            nw1 = *(const short8*)(p + (size_t)(1 * 8) * 512);
            nw2 = *(const short8*)(p + (size_t)(2 * 8) * 512);
            nw3 = *(const short8*)(p + (size_t)(3 * 8) * 512);
        }
        short8 a0 = *(const short8*)&H[ln15][kt * 32 + kg * 8];
        short8 a1 = *(const short8*)&H[16 + ln15][kt * 32 + kg * 8];
        acc2[0][0] = __builtin_amdgcn_mfma_f32_16x16x32_bf16(a0, w0, acc2[0][0], 0, 0, 0);
        acc2[0][1] = __builtin_amdgcn_mfma_f32_16x16x32_bf16(a0, w1, acc2[0][1], 0, 0, 0);
        acc2[0][2] = __builtin_amdgcn_mfma_f32_16x16x32_bf16(a0, w2, acc2[0][2], 0, 0, 0);
        acc2[0][3] = __builtin_amdgcn_mfma_f32_16x16x32_bf16(a0, w3, acc2[0][3], 0, 0, 0);
        acc2[1][0] = __builtin_amdgcn_mfma_f32_16x16x32_bf16(a1, w0, acc2[1][0], 0, 0, 0);
        acc2[1][1] = __builtin_amdgcn_mfma_f32_16x16x32_bf16(a1, w1, acc2[1][1], 0, 0, 0);
        acc2[1][2] = __builtin_amdgcn_mfma_f32_16x16x32_bf16(a1, w2, acc2[1][2], 0, 0, 0);
        acc2[1][3] = __builtin_amdgcn_mfma_f32_16x16x32_bf16(a1, w3, acc2[1][3], 0, 0, 0);
        w0 = nw0; w1 = nw1; w2 = nw2; w3 = nw3;
    }

    // ---- epilogue: relu -> *w_t -> reduce over e -> softplus
    float wt[4];
#pragma unroll
    for (int et = 0; et < 4; ++et) wt[et] = w_t[w * 64 + et * 16 + ln15];
#pragma unroll
    for (int Mt = 0; Mt < 2; ++Mt)
#pragma unroll
        for (int reg = 0; reg < 4; ++reg) {
            float v = 0.f;
#pragma unroll
            for (int et = 0; et < 4; ++et)
                v = fmaf(fmaxf(acc2[Mt][et][reg], 0.f), wt[et], v);
#pragma unroll
            for (int m = 1; m < 16; m <<= 1) v += __shfl_xor(v, m);
            if (ln15 == 0) s_dec[w][Mt * 16 + kg * 4 + reg] = v;
        }
    __syncthreads();
    if (tid < RPB) {
        float tot = s_dec[0][tid] + s_dec[1][tid] + s_dec[2][tid] + s_dec[3][tid] + b_t[0];
        float o = fmaxf(tot, 0.0f) + log1pf(expf(-fabsf(tot)));   // softplus
        out[(size_t)blk * RPB + tid] = o;
    }
}

// ---------------------------------------------------------------------------
extern "C" void kernel_launch(void* const* d_in, const int* in_sizes, int n_in,
                              void* d_out, int out_size, void* d_ws, size_t ws_size,
                              hipStream_t stream) {
    // inputs: 0 event_type(i32) 1 event_time(f32) 2 arrival_times(f32)
    //         3 W_in 4 w_t 5 b_t 6 ln_gamma 7 ln_beta
    const float* t   = (const float*)d_in[1];
    const float* W   = (const float*)d_in[3];
    const float* wt  = (const float*)d_in[4];
    const float* bt  = (const float*)d_in[5];
    const float* gam = (const float*)d_in[6];
    const float* bet = (const float*)d_in[7];
    float* out = (float*)d_out;

    char* ws = (char*)d_ws;
    unsigned short* emb5  = (unsigned short*)ws;                        // 8 MiB
    unsigned short* w5    = (unsigned short*)(ws + (size_t)8388608);    // 128 KiB
    int*            jcmin = (int*)(ws + (size_t)8519680);               // 2 KiB

    embt_kernel<<<dim3(512), dim3(256), 0, stream>>>(t, W, emb5, w5, jcmin);
    fused_kernel<<<dim3(NBLK), dim3(256), 0, stream>>>(
        t, emb5, w5, jcmin, gam, bet, wt, bt, out);
}